// Round 1
// baseline (1327.981 us; speedup 1.0000x reference)
//
#include <hip/hip_runtime.h>
#include <cstdint>
#include <cstddef>

#define B 32
#define U 1024
#define M_BANK 65536
#define FOURU 4096
#define FIVEU 5120

// ---- output slot offsets (floats) ----
#define R_OUT   0
#define H_OUT   32768
#define C_OUT   65536
#define MEM_OUT 98304
#define WU_OUT  67207168
#define WLU_OUT 69304320
#define WR_OUT  71401472

// ---- scratch inside mem_new slot (dead before k3b writes it) ----
#define ZS_OFF 0         // z: 32*5120
#define XT_OFF 163840    // xT: 1024*32
#define HT_OFF 196608    // hT
#define RT_OFF 229376    // rT
#define HN_OFF 262144    // hn: 32*1024  (ends 294912)

// ---- ws offsets (floats) ----
#define WS_RUN    0       // r_unnorm 32768
#define WS_ROWSUM 32768   // 32
#define WS_NTH    32800   // 32
#define WS_PMIN1  32832   // 256
#define WS_PMIN2  33088   // 256
#define WS_PIDX   33344   // 256 (int)
#define WS_SI     33600   // 1 (int)
#define WS_MEMSI  33664   // 1024
#define WS_MSUMSQ 34688   // 65536  (ends 100224 floats = ~392KB)

__device__ __forceinline__ float hsig(float x) {
    return fminf(fmaxf(0.2f * x + 0.5f, 0.f), 1.f);
}

// ------------------------------------------------------------------
// K0: zero/init accumulators. sim buffer (wr slot), z (bias), r_un, msumsq, rowsum
__global__ __launch_bounds__(256) void k0_init(float* out, float* ws, const float* bias) {
    const int N1 = 2097152;           // wr slot (sim accum) -> 0
    const int N2 = N1 + 163840;       // z init
    const int N3 = N2 + 32768;        // r_unnorm
    const int N4 = N3 + 65536;        // msumsq
    const int N5 = N4 + 32;           // rowsum
    int stride = gridDim.x * blockDim.x;
    for (int idx = blockIdx.x * blockDim.x + threadIdx.x; idx < N5; idx += stride) {
        if (idx < N1) {
            out[WR_OUT + idx] = 0.f;
        } else if (idx < N2) {
            int i2 = idx - N1;
            int j = i2 % FIVEU;
            out[MEM_OUT + ZS_OFF + i2] = (j < FOURU) ? bias[j] : 0.f;
        } else if (idx < N3) {
            ws[WS_RUN + (idx - N2)] = 0.f;
        } else if (idx < N4) {
            ws[WS_MSUMSQ + (idx - N3)] = 0.f;
        } else {
            ws[WS_ROWSUM + (idx - N4)] = 0.f;
        }
    }
}

// ------------------------------------------------------------------
// K_tr: transpose x, h_tm1, r_tm1 (32x1024 -> 1024x32) into mem_new scratch
__global__ __launch_bounds__(256) void k_tr(const float* x, const float* h, const float* r,
                                            float* scratch) {
    __shared__ float t[32][65];
    int arr = blockIdx.x >> 4;
    int kt = blockIdx.x & 15;
    const float* src = (arr == 0) ? x : ((arr == 1) ? h : r);
    float* dst = scratch + ((arr == 0) ? XT_OFF : ((arr == 1) ? HT_OFF : RT_OFF));
    int k0 = kt * 64;
    #pragma unroll
    for (int i = 0; i < 8; i++) {
        int q = threadIdx.x + 256 * i;
        int b = q >> 6, kk = q & 63;
        t[b][kk] = src[b * U + k0 + kk];
    }
    __syncthreads();
    #pragma unroll
    for (int i = 0; i < 8; i++) {
        int q = threadIdx.x + 256 * i;
        int kk = q >> 5, b = q & 31;
        dst[(k0 + kk) * 32 + b] = t[b][kk];
    }
}

// ------------------------------------------------------------------
// K1: gates GEMM. z[b][j] += x@kernel + h@Rk[:, :4U]  (j<4096)
//                 z[b][4096+u] += r@Rk[:, 4U:]        (j>=4096)
// lanes->j (coalesced weights), xT/hT/rT rows are wave-uniform (s_load path)
__global__ __launch_bounds__(256) void k1_gates(const float* kern, const float* rk,
                                                const float* scratch, float* z) {
    int j = blockIdx.x * 256 + threadIdx.x;
    int k0 = blockIdx.y * 128;
    const float* xT = scratch + XT_OFF;
    const float* hT = scratch + HT_OFF;
    const float* rT = scratch + RT_OFF;
    float acc[32];
    #pragma unroll
    for (int b = 0; b < 32; b++) acc[b] = 0.f;
    if (j < FOURU) {
        for (int k = k0; k < k0 + 128; k++) {
            float w1 = kern[(size_t)k * FOURU + j];
            float w2 = rk[(size_t)k * FIVEU + j];
            const float* xr = xT + k * 32;
            const float* hr = hT + k * 32;
            #pragma unroll
            for (int b = 0; b < 32; b++) acc[b] += xr[b] * w1 + hr[b] * w2;
        }
    } else {
        for (int k = k0; k < k0 + 128; k++) {
            float w2 = rk[(size_t)k * FIVEU + j];
            const float* rr = rT + k * 32;
            #pragma unroll
            for (int b = 0; b < 32; b++) acc[b] += rr[b] * w2;
        }
    }
    #pragma unroll
    for (int b = 0; b < 32; b++) atomicAdd(&z[b * FIVEU + j], acc[b]);
}

// ------------------------------------------------------------------
// K2: gate nonlinearity, c, h, normalized h. One block per batch row.
__global__ __launch_bounds__(256) void k2_gates(const float* z, const float* c_tm1,
                                                float* out, float* hn) {
    int b = blockIdx.x;
    const float* zb = z + b * FIVEU;
    float hv[4], cv[4];
    float ss = 0.f;
    #pragma unroll
    for (int i = 0; i < 4; i++) {
        int u = threadIdx.x + 256 * i;
        float zi = zb[u], zf = zb[1024 + u], zc = zb[2048 + u], zo = zb[3072 + u], ri = zb[4096 + u];
        float ig = hsig(zi + ri);
        float fg = hsig(zf);
        float og = hsig(zo);
        float c = fg * c_tm1[b * U + u] + ig * tanhf(zc);
        float h = og * tanhf(c);
        cv[i] = c; hv[i] = h; ss += h * h;
    }
    __shared__ float red[256];
    red[threadIdx.x] = ss;
    __syncthreads();
    for (int s = 128; s > 0; s >>= 1) {
        if (threadIdx.x < s) red[threadIdx.x] += red[threadIdx.x + s];
        __syncthreads();
    }
    float rn = rsqrtf(fmaxf(red[0], 1e-12f));
    #pragma unroll
    for (int i = 0; i < 4; i++) {
        int u = threadIdx.x + 256 * i;
        out[C_OUT + b * U + u] = cv[i];
        out[H_OUT + b * U + u] = hv[i];
        hn[b * U + u] = hv[i] * rn;
    }
}

// ------------------------------------------------------------------
// K_ww: wwT[m][b] = sg*wr_prev + (1-sg)*wlu, transposed via LDS (into wlu slot)
__global__ __launch_bounds__(256) void k_ww(const float* wr_prev, const float* wlu,
                                            const float* wg, float* wwT) {
    __shared__ float t2[32][257];
    int m0 = blockIdx.x * 256;
    int t = threadIdx.x;
    float sg = 1.f / (1.f + expf(-wg[0]));
    for (int b = 0; b < 32; b++) {
        size_t g = (size_t)b * M_BANK + m0 + t;
        t2[b][t] = sg * wr_prev[g] + (1.f - sg) * wlu[g];
    }
    __syncthreads();
    #pragma unroll
    for (int i = 0; i < 32; i++) {
        int q = t + 256 * i;
        int m = q >> 5, b = q & 31;
        wwT[(size_t)(m0 + m) * 32 + b] = t2[b][m];
    }
}

// ------------------------------------------------------------------
// K3a: sim partial GEMM. Tile: 32b x 256m, u-split by 4 (grid.y). 8x8 register
// blocking (0.25 LDS reads/FMA). Also accumulates per-row sumsq of mem.
__global__ __launch_bounds__(128) void k3a_sim(const float* mem, const float* hn,
                                               float* sim, float* msumsq) {
    __shared__ float mc[16][257];
    __shared__ float hs[16][33];
    __shared__ float ps[8][132];
    int mt0 = blockIdx.x * 256;
    int us0 = blockIdx.y * 256;
    int t = threadIdx.x;
    int bg = t >> 5;     // 0..3
    int mg = t & 31;     // 0..31
    float acc[8][8];
    #pragma unroll
    for (int a = 0; a < 8; a++)
        #pragma unroll
        for (int c = 0; c < 8; c++) acc[a][c] = 0.f;
    float sq[8];
    #pragma unroll
    for (int a = 0; a < 8; a++) sq[a] = 0.f;

    for (int uc = 0; uc < 16; uc++) {
        int u0 = us0 + uc * 16;
        #pragma unroll
        for (int i = 0; i < 8; i++) {
            int q = t + 128 * i;
            int m = q >> 2, u4 = q & 3;
            float4 v = *(const float4*)&mem[(size_t)(mt0 + m) * U + u0 + u4 * 4];
            mc[u4 * 4 + 0][m] = v.x;
            mc[u4 * 4 + 1][m] = v.y;
            mc[u4 * 4 + 2][m] = v.z;
            mc[u4 * 4 + 3][m] = v.w;
            sq[i] += v.x * v.x + v.y * v.y + v.z * v.z + v.w * v.w;
        }
        #pragma unroll
        for (int i = 0; i < 4; i++) {
            int q = t + 128 * i;
            int uu = q & 15, b = q >> 4;
            hs[uu][b] = hn[b * U + u0 + uu];
        }
        __syncthreads();
        #pragma unroll
        for (int uu = 0; uu < 16; uu++) {
            float hv[8], mv[8];
            #pragma unroll
            for (int jb = 0; jb < 8; jb++) hv[jb] = hs[uu][bg + 4 * jb];
            #pragma unroll
            for (int jm = 0; jm < 8; jm++) mv[jm] = mc[uu][mg + 32 * jm];
            #pragma unroll
            for (int jb = 0; jb < 8; jb++)
                #pragma unroll
                for (int jm = 0; jm < 8; jm++) acc[jb][jm] += hv[jb] * mv[jm];
        }
        __syncthreads();
    }
    // reduce per-row sumsq: thread t loaded rows (t>>2)+32*i, quarter (t&3)
    #pragma unroll
    for (int i = 0; i < 8; i++) ps[i][t] = sq[i];
    __syncthreads();
    #pragma unroll
    for (int rr = 0; rr < 2; rr++) {
        int m = t + 128 * rr;
        int slot = m >> 5;
        int base = (m & 31) * 4;
        float s = ps[slot][base] + ps[slot][base + 1] + ps[slot][base + 2] + ps[slot][base + 3];
        atomicAdd(&msumsq[mt0 + m], s);
    }
    #pragma unroll
    for (int jb = 0; jb < 8; jb++) {
        int b = bg + 4 * jb;
        #pragma unroll
        for (int jm = 0; jm < 8; jm++) {
            int m = mg + 32 * jm;
            atomicAdd(&sim[(size_t)b * M_BANK + mt0 + m], acc[jb][jm]);
        }
    }
}

// ------------------------------------------------------------------
// K3a2: e = exp(sim * rsqrt(msumsq)) in place (wr slot); write eT (wu slot);
// accumulate rowsum.
__global__ __launch_bounds__(256) void k3a2_exp(float* wr, const float* msumsq,
                                                float* eT, float* rowsum) {
    __shared__ float t2[32][257];
    __shared__ float rn_s[256];
    int m0 = blockIdx.x * 256;
    int t = threadIdx.x;
    rn_s[t] = rsqrtf(fmaxf(msumsq[m0 + t], 1e-12f));
    __syncthreads();
    for (int b = 0; b < 32; b++) {
        size_t g = (size_t)b * M_BANK + m0 + t;
        float e = expf(wr[g] * rn_s[t]);
        wr[g] = e;
        t2[b][t] = e;
    }
    __syncthreads();
    if (t < 32) {
        float s = 0.f;
        for (int m = 0; m < 256; m++) s += t2[t][m];
        atomicAdd(&rowsum[t], s);
    }
    #pragma unroll
    for (int i = 0; i < 32; i++) {
        int q = t + 256 * i;
        int m = q >> 5, b = q & 31;
        eT[(size_t)(m0 + m) * 32 + b] = t2[b][m];
    }
}

// ------------------------------------------------------------------
// K3b: fused r-accumulate + mem_new write. lanes->u (coalesced mem rows),
// eT/wwT rows are wave-uniform -> scalar loads. h cached in 32 VGPRs.
__global__ __launch_bounds__(256) void k3b_rmem(const float* mem, const float* eT,
                                                const float* wwT, const float* h,
                                                float* mem_new, float* r_un) {
    int mt0 = blockIdx.x * 512;
    int u = blockIdx.y * 256 + threadIdx.x;
    float hreg[32], accr[32];
    #pragma unroll
    for (int b = 0; b < 32; b++) {
        hreg[b] = h[b * U + u];
        accr[b] = 0.f;
    }
    for (int m = mt0; m < mt0 + 512; m++) {
        float mv = mem[(size_t)m * U + u];
        const float* wwr = wwT + (size_t)m * 32;
        const float* er = eT + (size_t)m * 32;
        float o = mv;
        #pragma unroll
        for (int b = 0; b < 32; b++) {
            o += wwr[b] * hreg[b];
            accr[b] += er[b] * mv;
        }
        mem_new[(size_t)m * U + u] = o;
    }
    #pragma unroll
    for (int b = 0; b < 32; b++) atomicAdd(&r_un[b * U + u], accr[b]);
}

// ------------------------------------------------------------------
// K4: wr final, wu_new, per-chunk two-smallest (+argmin idx), r finalize.
// grid: 32 rows x 8 chunks of 8192
__global__ __launch_bounds__(256) void k4_wu(const float* wu, const float* wr_prev,
                                             const float* wlu, const float* wg,
                                             float* ws, float* out) {
    int b = blockIdx.x >> 3;
    int ch = blockIdx.x & 7;
    int t = threadIdx.x;
    float sg = 1.f / (1.f + expf(-wg[0]));
    float inv = 1.f / ws[WS_ROWSUM + b];
    float m1 = 1e30f, m2 = 1e30f;
    int ix = 0;
    int base = ch * 8192;
    for (int i = 0; i < 32; i++) {
        int m = base + t + 256 * i;
        size_t g = (size_t)b * M_BANK + m;
        float ev = out[WR_OUT + g];
        float wrv = ev * inv;
        float wwv = sg * wr_prev[g] + (1.f - sg) * wlu[g];
        float wun = 0.5f * wu[g] + wrv + wwv;
        out[WR_OUT + g] = wrv;
        out[WU_OUT + g] = wun;
        if (wun < m1) { m2 = m1; m1 = wun; ix = m; }
        else if (wun < m2) { m2 = wun; }
    }
    __shared__ float a1[256], a2[256];
    __shared__ int ai[256];
    a1[t] = m1; a2[t] = m2; ai[t] = ix;
    __syncthreads();
    if (t == 0) {
        float r1 = a1[0], r2 = a2[0];
        int rix = ai[0];
        for (int j = 1; j < 256; j++) {
            float b1 = a1[j], b2 = a2[j];
            int bix = ai[j];
            if (b1 < r1)       { r2 = fminf(r1, b2); r1 = b1; rix = bix; }
            else if (b1 == r1) { r2 = r1; if (bix < rix) rix = bix; }
            else               { r2 = fminf(r2, b1); }
        }
        ws[WS_PMIN1 + blockIdx.x] = r1;
        ws[WS_PMIN2 + blockIdx.x] = r2;
        ((int*)ws)[WS_PIDX + blockIdx.x] = rix;
    }
    if (ch == 0) {
        const float* r_un = ws + WS_RUN;
        #pragma unroll
        for (int i = 0; i < 4; i++) {
            int u = t + 256 * i;
            out[R_OUT + b * U + u] = r_un[b * U + u] * inv;
        }
    }
}

// ------------------------------------------------------------------
// K5: final per-row merge -> nth_smallest; global smallest_index; precompute
// replacement row for mem_new (ww.T@h at row si).
__global__ __launch_bounds__(256) void k5_reduce(float* ws, const float* wwT, const float* h) {
    __shared__ int sidx[32];
    __shared__ int s_si;
    int t = threadIdx.x;
    if (t < 32) {
        float m1 = 1e30f, m2 = 1e30f;
        int ix = 0x7fffffff;
        for (int c = 0; c < 8; c++) {
            float b1 = ws[WS_PMIN1 + t * 8 + c];
            float b2 = ws[WS_PMIN2 + t * 8 + c];
            int bix = ((const int*)ws)[WS_PIDX + t * 8 + c];
            if (b1 < m1)       { m2 = fminf(m1, b2); m1 = b1; ix = bix; }
            else if (b1 == m1) { m2 = m1; if (bix < ix) ix = bix; }
            else               { m2 = fminf(m2, b1); }
        }
        ws[WS_NTH + t] = m2;
        sidx[t] = ix;
    }
    __syncthreads();
    if (t == 0) {
        int si = sidx[0];
        for (int b = 1; b < 32; b++) si = min(si, sidx[b]);
        s_si = si;
        ((int*)ws)[WS_SI] = si;
    }
    __syncthreads();
    int si = s_si;
    for (int u = t; u < U; u += 256) {
        float s = 0.f;
        #pragma unroll
        for (int b = 0; b < 32; b++) s += wwT[(size_t)si * 32 + b] * h[b * U + u];
        ws[WS_MEMSI + u] = s;
    }
}

// ------------------------------------------------------------------
// K6: wlu_new = (wu_new <= nth); rewrite mem_new row si (keep=0 row).
__global__ __launch_bounds__(256) void k6_final(float* out, const float* ws) {
    if (blockIdx.x < 1024) {
        int b = blockIdx.x >> 5;
        int ch = blockIdx.x & 31;
        float nth = ws[WS_NTH + b];
        #pragma unroll
        for (int i = 0; i < 8; i++) {
            int m = ch * 2048 + threadIdx.x + 256 * i;
            size_t g = (size_t)b * M_BANK + m;
            out[WLU_OUT + g] = (out[WU_OUT + g] <= nth) ? 1.f : 0.f;
        }
    } else {
        int j = blockIdx.x - 1024;
        int si = ((const int*)ws)[WS_SI];
        int u = j * 256 + threadIdx.x;
        out[MEM_OUT + (size_t)si * U + u] = ws[WS_MEMSI + u];
    }
}

// ------------------------------------------------------------------
extern "C" void kernel_launch(void* const* d_in, const int* in_sizes, int n_in,
                              void* d_out, int out_size, void* d_ws, size_t ws_size,
                              hipStream_t stream) {
    (void)in_sizes; (void)n_in; (void)out_size; (void)ws_size;
    const float* x       = (const float*)d_in[0];
    const float* h_tm1   = (const float*)d_in[1];
    const float* c_tm1   = (const float*)d_in[2];
    const float* r_tm1   = (const float*)d_in[3];
    const float* mem     = (const float*)d_in[4];
    const float* wu      = (const float*)d_in[5];
    const float* wlu     = (const float*)d_in[6];
    const float* wr_prev = (const float*)d_in[7];
    const float* kern    = (const float*)d_in[8];
    const float* rk      = (const float*)d_in[9];
    const float* bias    = (const float*)d_in[10];
    const float* wg      = (const float*)d_in[11];
    float* out = (float*)d_out;
    float* ws  = (float*)d_ws;

    float* scratch = out + MEM_OUT;          // z/xT/hT/rT/hn live here pre-k3b
    float* zbuf    = scratch + ZS_OFF;
    float* hn      = scratch + HN_OFF;
    float* simbuf  = out + WR_OUT;           // sim accum, then e, then wr
    float* eT      = out + WU_OUT;           // transposed e (dead before k4 writes wu)
    float* wwT     = out + WLU_OUT;          // transposed ww (dead before k6 writes wlu)

    k0_init<<<dim3(2048), dim3(256), 0, stream>>>(out, ws, bias);
    k_tr<<<dim3(48), dim3(256), 0, stream>>>(x, h_tm1, r_tm1, scratch);
    k1_gates<<<dim3(20, 8), dim3(256), 0, stream>>>(kern, rk, scratch, zbuf);
    k2_gates<<<dim3(32), dim3(256), 0, stream>>>(zbuf, c_tm1, out, hn);
    k_ww<<<dim3(256), dim3(256), 0, stream>>>(wr_prev, wlu, wg, wwT);
    k3a_sim<<<dim3(256, 4), dim3(128), 0, stream>>>(mem, hn, simbuf, ws + WS_MSUMSQ);
    k3a2_exp<<<dim3(256), dim3(256), 0, stream>>>(simbuf, ws + WS_MSUMSQ, eT, ws + WS_ROWSUM);
    k3b_rmem<<<dim3(128, 4), dim3(256), 0, stream>>>(mem, eT, wwT, out + H_OUT,
                                                     out + MEM_OUT, ws + WS_RUN);
    k4_wu<<<dim3(256), dim3(256), 0, stream>>>(wu, wr_prev, wlu, wg, ws, out);
    k5_reduce<<<dim3(1), dim3(256), 0, stream>>>(ws, wwT, out + H_OUT);
    k6_final<<<dim3(1028), dim3(256), 0, stream>>>(out, ws);
}

// Round 2
// 997.781 us; speedup vs baseline: 1.3309x; 1.3309x over previous
//
#include <hip/hip_runtime.h>
#include <cstdint>
#include <cstddef>

#define B 32
#define U 1024
#define M_BANK 65536
#define FOURU 4096
#define FIVEU 5120

// ---- output slot offsets (floats) ----
#define R_OUT   0
#define H_OUT   32768
#define C_OUT   65536
#define MEM_OUT 98304
#define WU_OUT  67207168
#define WLU_OUT 69304320
#define WR_OUT  71401472

// ---- scratch inside mem_new slot (dead before k3b writes it) ----
#define ZS_OFF 0         // z: 32*5120
#define XT_OFF 163840    // xT: 1024*32
#define HT_OFF 196608    // hT
#define RT_OFF 229376    // rT
#define HN_OFF 262144    // hn: 32*1024  (ends 294912)

// ---- ws offsets (floats) ----
#define WS_RUN    0       // r_unnorm 32768
#define WS_ROWSUM 32768   // 32
#define WS_NTH    32800   // 32
#define WS_PMIN1  32832   // 256
#define WS_PMIN2  33088   // 256
#define WS_PIDX   33344   // 256 (int)
#define WS_SI     33600   // 1 (int)
#define WS_MEMSI  33664   // 1024
#define WS_MSUMSQ 34688   // 65536  (ends 100224 floats = ~392KB)

__device__ __forceinline__ float hsig(float x) {
    return fminf(fmaxf(0.2f * x + 0.5f, 0.f), 1.f);
}

// ------------------------------------------------------------------
// K0: zero/init accumulators. sim buffer (wr slot), z (bias), r_un, msumsq, rowsum
__global__ __launch_bounds__(256) void k0_init(float* out, float* ws, const float* bias) {
    const int N1 = 2097152;           // wr slot (sim accum) -> 0
    const int N2 = N1 + 163840;       // z init
    const int N3 = N2 + 32768;        // r_unnorm
    const int N4 = N3 + 65536;        // msumsq
    const int N5 = N4 + 32;           // rowsum
    int stride = gridDim.x * blockDim.x;
    for (int idx = blockIdx.x * blockDim.x + threadIdx.x; idx < N5; idx += stride) {
        if (idx < N1) {
            out[WR_OUT + idx] = 0.f;
        } else if (idx < N2) {
            int i2 = idx - N1;
            int j = i2 % FIVEU;
            out[MEM_OUT + ZS_OFF + i2] = (j < FOURU) ? bias[j] : 0.f;
        } else if (idx < N3) {
            ws[WS_RUN + (idx - N2)] = 0.f;
        } else if (idx < N4) {
            ws[WS_MSUMSQ + (idx - N3)] = 0.f;
        } else {
            ws[WS_ROWSUM + (idx - N4)] = 0.f;
        }
    }
}

// ------------------------------------------------------------------
// K_tr: transpose x, h_tm1, r_tm1 (32x1024 -> 1024x32) into mem_new scratch
__global__ __launch_bounds__(256) void k_tr(const float* x, const float* h, const float* r,
                                            float* scratch) {
    __shared__ float t[32][65];
    int arr = blockIdx.x >> 4;
    int kt = blockIdx.x & 15;
    const float* src = (arr == 0) ? x : ((arr == 1) ? h : r);
    float* dst = scratch + ((arr == 0) ? XT_OFF : ((arr == 1) ? HT_OFF : RT_OFF));
    int k0 = kt * 64;
    #pragma unroll
    for (int i = 0; i < 8; i++) {
        int q = threadIdx.x + 256 * i;
        int b = q >> 6, kk = q & 63;
        t[b][kk] = src[b * U + k0 + kk];
    }
    __syncthreads();
    #pragma unroll
    for (int i = 0; i < 8; i++) {
        int q = threadIdx.x + 256 * i;
        int kk = q >> 5, b = q & 31;
        dst[(k0 + kk) * 32 + b] = t[b][kk];
    }
}

// ------------------------------------------------------------------
// K1: gates GEMM. z[b][j] += x@kernel + h@Rk[:, :4U]  (j<4096)
//                 z[b][4096+u] += r@Rk[:, 4U:]        (j>=4096)
// lanes->j (coalesced weights); xT/hT/rT tiles staged in LDS, read as
// wave-uniform broadcast ds_reads (conflict-free).
__global__ __launch_bounds__(256) void k1_gates(const float* kern, const float* rk,
                                                const float* scratch, float* z) {
    __shared__ float sa[128][32];
    __shared__ float sb[128][32];
    int t = threadIdx.x;
    int j = blockIdx.x * 256 + t;
    int k0 = blockIdx.y * 128;
    bool main_path = (blockIdx.x < 16);   // j < 4096, wave-uniform
    const float* aT = scratch + (main_path ? XT_OFF : RT_OFF);
    const float* hT = scratch + HT_OFF;

    const float4* asrc = (const float4*)(aT + k0 * 32);
    #pragma unroll
    for (int i = 0; i < 4; i++) ((float4*)sa)[t + 256 * i] = asrc[t + 256 * i];
    if (main_path) {
        const float4* bsrc = (const float4*)(hT + k0 * 32);
        #pragma unroll
        for (int i = 0; i < 4; i++) ((float4*)sb)[t + 256 * i] = bsrc[t + 256 * i];
    }
    __syncthreads();

    float acc[32];
    #pragma unroll
    for (int b = 0; b < 32; b++) acc[b] = 0.f;
    if (main_path) {
        for (int k = 0; k < 128; k++) {
            float w1 = kern[(size_t)(k0 + k) * FOURU + j];
            float w2 = rk[(size_t)(k0 + k) * FIVEU + j];
            #pragma unroll
            for (int b = 0; b < 32; b++) acc[b] += sa[k][b] * w1 + sb[k][b] * w2;
        }
    } else {
        for (int k = 0; k < 128; k++) {
            float w2 = rk[(size_t)(k0 + k) * FIVEU + j];
            #pragma unroll
            for (int b = 0; b < 32; b++) acc[b] += sa[k][b] * w2;
        }
    }
    #pragma unroll
    for (int b = 0; b < 32; b++) atomicAdd(&z[b * FIVEU + j], acc[b]);
}

// ------------------------------------------------------------------
// K2: gate nonlinearity, c, h, normalized h. One block per batch row.
__global__ __launch_bounds__(256) void k2_gates(const float* z, const float* c_tm1,
                                                float* out, float* hn) {
    int b = blockIdx.x;
    const float* zb = z + b * FIVEU;
    float hv[4], cv[4];
    float ss = 0.f;
    #pragma unroll
    for (int i = 0; i < 4; i++) {
        int u = threadIdx.x + 256 * i;
        float zi = zb[u], zf = zb[1024 + u], zc = zb[2048 + u], zo = zb[3072 + u], ri = zb[4096 + u];
        float ig = hsig(zi + ri);
        float fg = hsig(zf);
        float og = hsig(zo);
        float c = fg * c_tm1[b * U + u] + ig * tanhf(zc);
        float h = og * tanhf(c);
        cv[i] = c; hv[i] = h; ss += h * h;
    }
    __shared__ float red[256];
    red[threadIdx.x] = ss;
    __syncthreads();
    for (int s = 128; s > 0; s >>= 1) {
        if (threadIdx.x < s) red[threadIdx.x] += red[threadIdx.x + s];
        __syncthreads();
    }
    float rn = rsqrtf(fmaxf(red[0], 1e-12f));
    #pragma unroll
    for (int i = 0; i < 4; i++) {
        int u = threadIdx.x + 256 * i;
        out[C_OUT + b * U + u] = cv[i];
        out[H_OUT + b * U + u] = hv[i];
        hn[b * U + u] = hv[i] * rn;
    }
}

// ------------------------------------------------------------------
// K_ww: wwT[m][b] = sg*wr_prev + (1-sg)*wlu, transposed via LDS (into wlu slot)
__global__ __launch_bounds__(256) void k_ww(const float* wr_prev, const float* wlu,
                                            const float* wg, float* wwT) {
    __shared__ float t2[32][257];
    int m0 = blockIdx.x * 256;
    int t = threadIdx.x;
    float sg = 1.f / (1.f + expf(-wg[0]));
    for (int b = 0; b < 32; b++) {
        size_t g = (size_t)b * M_BANK + m0 + t;
        t2[b][t] = sg * wr_prev[g] + (1.f - sg) * wlu[g];
    }
    __syncthreads();
    #pragma unroll
    for (int i = 0; i < 32; i++) {
        int q = t + 256 * i;
        int m = q >> 5, b = q & 31;
        wwT[(size_t)(m0 + m) * 32 + b] = t2[b][m];
    }
}

// ------------------------------------------------------------------
// K3a: sim partial GEMM. Tile: 32b x 256m, u-split by 4 (grid.y). 8x8 register
// blocking (0.25 LDS reads/FMA). Also accumulates per-row sumsq of mem.
__global__ __launch_bounds__(128) void k3a_sim(const float* mem, const float* hn,
                                               float* sim, float* msumsq) {
    __shared__ float mc[16][257];
    __shared__ float hs[16][33];
    __shared__ float ps[8][132];
    int mt0 = blockIdx.x * 256;
    int us0 = blockIdx.y * 256;
    int t = threadIdx.x;
    int bg = t >> 5;     // 0..3
    int mg = t & 31;     // 0..31
    float acc[8][8];
    #pragma unroll
    for (int a = 0; a < 8; a++)
        #pragma unroll
        for (int c = 0; c < 8; c++) acc[a][c] = 0.f;
    float sq[8];
    #pragma unroll
    for (int a = 0; a < 8; a++) sq[a] = 0.f;

    for (int uc = 0; uc < 16; uc++) {
        int u0 = us0 + uc * 16;
        #pragma unroll
        for (int i = 0; i < 8; i++) {
            int q = t + 128 * i;
            int m = q >> 2, u4 = q & 3;
            float4 v = *(const float4*)&mem[(size_t)(mt0 + m) * U + u0 + u4 * 4];
            mc[u4 * 4 + 0][m] = v.x;
            mc[u4 * 4 + 1][m] = v.y;
            mc[u4 * 4 + 2][m] = v.z;
            mc[u4 * 4 + 3][m] = v.w;
            sq[i] += v.x * v.x + v.y * v.y + v.z * v.z + v.w * v.w;
        }
        #pragma unroll
        for (int i = 0; i < 4; i++) {
            int q = t + 128 * i;
            int uu = q & 15, b = q >> 4;
            hs[uu][b] = hn[b * U + u0 + uu];
        }
        __syncthreads();
        #pragma unroll
        for (int uu = 0; uu < 16; uu++) {
            float hv[8], mv[8];
            #pragma unroll
            for (int jb = 0; jb < 8; jb++) hv[jb] = hs[uu][bg + 4 * jb];
            #pragma unroll
            for (int jm = 0; jm < 8; jm++) mv[jm] = mc[uu][mg + 32 * jm];
            #pragma unroll
            for (int jb = 0; jb < 8; jb++)
                #pragma unroll
                for (int jm = 0; jm < 8; jm++) acc[jb][jm] += hv[jb] * mv[jm];
        }
        __syncthreads();
    }
    // reduce per-row sumsq: thread t loaded rows (t>>2)+32*i, quarter (t&3)
    #pragma unroll
    for (int i = 0; i < 8; i++) ps[i][t] = sq[i];
    __syncthreads();
    #pragma unroll
    for (int rr = 0; rr < 2; rr++) {
        int m = t + 128 * rr;
        int slot = m >> 5;
        int base = (m & 31) * 4;
        float s = ps[slot][base] + ps[slot][base + 1] + ps[slot][base + 2] + ps[slot][base + 3];
        atomicAdd(&msumsq[mt0 + m], s);
    }
    #pragma unroll
    for (int jb = 0; jb < 8; jb++) {
        int b = bg + 4 * jb;
        #pragma unroll
        for (int jm = 0; jm < 8; jm++) {
            int m = mg + 32 * jm;
            atomicAdd(&sim[(size_t)b * M_BANK + mt0 + m], acc[jb][jm]);
        }
    }
}

// ------------------------------------------------------------------
// K3a2: e = exp(sim * rsqrt(msumsq)) in place (wr slot); write eT (wu slot);
// accumulate rowsum.
__global__ __launch_bounds__(256) void k3a2_exp(float* wr, const float* msumsq,
                                                float* eT, float* rowsum) {
    __shared__ float t2[32][257];
    __shared__ float rn_s[256];
    int m0 = blockIdx.x * 256;
    int t = threadIdx.x;
    rn_s[t] = rsqrtf(fmaxf(msumsq[m0 + t], 1e-12f));
    __syncthreads();
    for (int b = 0; b < 32; b++) {
        size_t g = (size_t)b * M_BANK + m0 + t;
        float e = expf(wr[g] * rn_s[t]);
        wr[g] = e;
        t2[b][t] = e;
    }
    __syncthreads();
    if (t < 32) {
        float s = 0.f;
        for (int m = 0; m < 256; m++) s += t2[t][m];
        atomicAdd(&rowsum[t], s);
    }
    #pragma unroll
    for (int i = 0; i < 32; i++) {
        int q = t + 256 * i;
        int m = q >> 5, b = q & 31;
        eT[(size_t)(m0 + m) * 32 + b] = t2[b][m];
    }
}

// ------------------------------------------------------------------
// K3b v2: fused r-accumulate + mem_new write. lanes->u (float2, coalesced),
// eT/wwT staged per-64-m-tile in LDS via coalesced float4 loads, consumed as
// broadcast ds_reads. h cached in 64 VGPRs (float2 x 32).
// grid: (M/512, U/512) = (128, 2); block 256.
__global__ __launch_bounds__(256) void k3b_rmem(const float* mem, const float* eT,
                                                const float* wwT, const float* h,
                                                float* mem_new, float* r_un) {
    __shared__ float sww[64][32];
    __shared__ float see[64][32];
    int t = threadIdx.x;
    int mt0 = blockIdx.x * 512;
    int u0 = blockIdx.y * 512 + t * 2;

    float2 hreg[32], accr[32];
    #pragma unroll
    for (int b = 0; b < 32; b++) {
        hreg[b] = *(const float2*)&h[b * U + u0];
        accr[b] = make_float2(0.f, 0.f);
    }

    for (int t8 = 0; t8 < 8; t8++) {
        int mbase = mt0 + t8 * 64;
        __syncthreads();
        const float4* esrc = (const float4*)(eT + (size_t)mbase * 32);
        const float4* wsrc = (const float4*)(wwT + (size_t)mbase * 32);
        ((float4*)see)[t]       = esrc[t];
        ((float4*)see)[t + 256] = esrc[t + 256];
        ((float4*)sww)[t]       = wsrc[t];
        ((float4*)sww)[t + 256] = wsrc[t + 256];
        __syncthreads();

        for (int mm = 0; mm < 64; mm++) {
            int m = mbase + mm;
            float2 mv = *(const float2*)&mem[(size_t)m * U + u0];
            float2 o = mv;
            #pragma unroll
            for (int b = 0; b < 32; b++) {
                float w = sww[mm][b];
                float e = see[mm][b];
                o.x += w * hreg[b].x;
                o.y += w * hreg[b].y;
                accr[b].x += e * mv.x;
                accr[b].y += e * mv.y;
            }
            *(float2*)&mem_new[(size_t)m * U + u0] = o;
        }
    }
    #pragma unroll
    for (int b = 0; b < 32; b++) {
        atomicAdd(&r_un[b * U + u0], accr[b].x);
        atomicAdd(&r_un[b * U + u0 + 1], accr[b].y);
    }
}

// ------------------------------------------------------------------
// K4: wr final, wu_new, per-chunk two-smallest (+argmin idx), r finalize.
// grid: 32 rows x 8 chunks of 8192
__global__ __launch_bounds__(256) void k4_wu(const float* wu, const float* wr_prev,
                                             const float* wlu, const float* wg,
                                             float* ws, float* out) {
    int b = blockIdx.x >> 3;
    int ch = blockIdx.x & 7;
    int t = threadIdx.x;
    float sg = 1.f / (1.f + expf(-wg[0]));
    float inv = 1.f / ws[WS_ROWSUM + b];
    float m1 = 1e30f, m2 = 1e30f;
    int ix = 0;
    int base = ch * 8192;
    for (int i = 0; i < 32; i++) {
        int m = base + t + 256 * i;
        size_t g = (size_t)b * M_BANK + m;
        float ev = out[WR_OUT + g];
        float wrv = ev * inv;
        float wwv = sg * wr_prev[g] + (1.f - sg) * wlu[g];
        float wun = 0.5f * wu[g] + wrv + wwv;
        out[WR_OUT + g] = wrv;
        out[WU_OUT + g] = wun;
        if (wun < m1) { m2 = m1; m1 = wun; ix = m; }
        else if (wun < m2) { m2 = wun; }
    }
    __shared__ float a1[256], a2[256];
    __shared__ int ai[256];
    a1[t] = m1; a2[t] = m2; ai[t] = ix;
    __syncthreads();
    if (t == 0) {
        float r1 = a1[0], r2 = a2[0];
        int rix = ai[0];
        for (int j = 1; j < 256; j++) {
            float b1 = a1[j], b2 = a2[j];
            int bix = ai[j];
            if (b1 < r1)       { r2 = fminf(r1, b2); r1 = b1; rix = bix; }
            else if (b1 == r1) { r2 = r1; if (bix < rix) rix = bix; }
            else               { r2 = fminf(r2, b1); }
        }
        ws[WS_PMIN1 + blockIdx.x] = r1;
        ws[WS_PMIN2 + blockIdx.x] = r2;
        ((int*)ws)[WS_PIDX + blockIdx.x] = rix;
    }
    if (ch == 0) {
        const float* r_un = ws + WS_RUN;
        #pragma unroll
        for (int i = 0; i < 4; i++) {
            int u = t + 256 * i;
            out[R_OUT + b * U + u] = r_un[b * U + u] * inv;
        }
    }
}

// ------------------------------------------------------------------
// K5: final per-row merge -> nth_smallest; global smallest_index; precompute
// replacement row for mem_new (ww.T@h at row si).
__global__ __launch_bounds__(256) void k5_reduce(float* ws, const float* wwT, const float* h) {
    __shared__ int sidx[32];
    __shared__ int s_si;
    int t = threadIdx.x;
    if (t < 32) {
        float m1 = 1e30f, m2 = 1e30f;
        int ix = 0x7fffffff;
        for (int c = 0; c < 8; c++) {
            float b1 = ws[WS_PMIN1 + t * 8 + c];
            float b2 = ws[WS_PMIN2 + t * 8 + c];
            int bix = ((const int*)ws)[WS_PIDX + t * 8 + c];
            if (b1 < m1)       { m2 = fminf(m1, b2); m1 = b1; ix = bix; }
            else if (b1 == m1) { m2 = m1; if (bix < ix) ix = bix; }
            else               { m2 = fminf(m2, b1); }
        }
        ws[WS_NTH + t] = m2;
        sidx[t] = ix;
    }
    __syncthreads();
    if (t == 0) {
        int si = sidx[0];
        for (int b = 1; b < 32; b++) si = min(si, sidx[b]);
        s_si = si;
        ((int*)ws)[WS_SI] = si;
    }
    __syncthreads();
    int si = s_si;
    for (int u = t; u < U; u += 256) {
        float s = 0.f;
        #pragma unroll
        for (int b = 0; b < 32; b++) s += wwT[(size_t)si * 32 + b] * h[b * U + u];
        ws[WS_MEMSI + u] = s;
    }
}

// ------------------------------------------------------------------
// K6: wlu_new = (wu_new <= nth); rewrite mem_new row si (keep=0 row).
__global__ __launch_bounds__(256) void k6_final(float* out, const float* ws) {
    if (blockIdx.x < 1024) {
        int b = blockIdx.x >> 5;
        int ch = blockIdx.x & 31;
        float nth = ws[WS_NTH + b];
        #pragma unroll
        for (int i = 0; i < 8; i++) {
            int m = ch * 2048 + threadIdx.x + 256 * i;
            size_t g = (size_t)b * M_BANK + m;
            out[WLU_OUT + g] = (out[WU_OUT + g] <= nth) ? 1.f : 0.f;
        }
    } else {
        int j = blockIdx.x - 1024;
        int si = ((const int*)ws)[WS_SI];
        int u = j * 256 + threadIdx.x;
        out[MEM_OUT + (size_t)si * U + u] = ws[WS_MEMSI + u];
    }
}

// ------------------------------------------------------------------
extern "C" void kernel_launch(void* const* d_in, const int* in_sizes, int n_in,
                              void* d_out, int out_size, void* d_ws, size_t ws_size,
                              hipStream_t stream) {
    (void)in_sizes; (void)n_in; (void)out_size; (void)ws_size;
    const float* x       = (const float*)d_in[0];
    const float* h_tm1   = (const float*)d_in[1];
    const float* c_tm1   = (const float*)d_in[2];
    const float* r_tm1   = (const float*)d_in[3];
    const float* mem     = (const float*)d_in[4];
    const float* wu      = (const float*)d_in[5];
    const float* wlu     = (const float*)d_in[6];
    const float* wr_prev = (const float*)d_in[7];
    const float* kern    = (const float*)d_in[8];
    const float* rk      = (const float*)d_in[9];
    const float* bias    = (const float*)d_in[10];
    const float* wg      = (const float*)d_in[11];
    float* out = (float*)d_out;
    float* ws  = (float*)d_ws;

    float* scratch = out + MEM_OUT;          // z/xT/hT/rT/hn live here pre-k3b
    float* zbuf    = scratch + ZS_OFF;
    float* hn      = scratch + HN_OFF;
    float* simbuf  = out + WR_OUT;           // sim accum, then e, then wr
    float* eT      = out + WU_OUT;           // transposed e (dead before k4 writes wu)
    float* wwT     = out + WLU_OUT;          // transposed ww (dead before k6 writes wlu)

    k0_init<<<dim3(2048), dim3(256), 0, stream>>>(out, ws, bias);
    k_tr<<<dim3(48), dim3(256), 0, stream>>>(x, h_tm1, r_tm1, scratch);
    k1_gates<<<dim3(20, 8), dim3(256), 0, stream>>>(kern, rk, scratch, zbuf);
    k2_gates<<<dim3(32), dim3(256), 0, stream>>>(zbuf, c_tm1, out, hn);
    k_ww<<<dim3(256), dim3(256), 0, stream>>>(wr_prev, wlu, wg, wwT);
    k3a_sim<<<dim3(256, 4), dim3(128), 0, stream>>>(mem, hn, simbuf, ws + WS_MSUMSQ);
    k3a2_exp<<<dim3(256), dim3(256), 0, stream>>>(simbuf, ws + WS_MSUMSQ, eT, ws + WS_ROWSUM);
    k3b_rmem<<<dim3(128, 2), dim3(256), 0, stream>>>(mem, eT, wwT, out + H_OUT,
                                                     out + MEM_OUT, ws + WS_RUN);
    k4_wu<<<dim3(256), dim3(256), 0, stream>>>(wu, wr_prev, wlu, wg, ws, out);
    k5_reduce<<<dim3(1), dim3(256), 0, stream>>>(ws, wwT, out + H_OUT);
    k6_final<<<dim3(1028), dim3(256), 0, stream>>>(out, ws);
}